// Round 11
// baseline (1129.654 us; speedup 1.0000x reference)
//
#include <hip/hip_runtime.h>
#include <cstddef>

constexpr int N_ = 65536;
constexpr int K_ = 16;
constexpr int E_ = N_ * K_;      // 1048576
constexpr int C_ = 64;
#define EPS_ 1e-5f
#define SW 68   // LDS row stride (words) for GEMM tiles
#define INV_N (1.f / 65536.f)
#define INV_E (1.f / 1048576.f)

typedef unsigned int uint_t;

// bf16 helpers (RNE pack, cheap unpack)
__device__ __forceinline__ uint_t bf16_rne(float f) {
    uint_t u = __float_as_uint(f);
    return (u + 0x7fffu + ((u >> 16) & 1u)) >> 16;
}
__device__ __forceinline__ float bf16_lo(uint_t p) { return __uint_as_float(p << 16); }
__device__ __forceinline__ float bf16_hi(uint_t p) { return __uint_as_float(p & 0xffff0000u); }

// scale/shift from raw accumulated {sum, sumsq}: acc[c]=sum, acc[nchp+c]=sumsq
__device__ __forceinline__ void bn_ss(const float* __restrict__ acc, int nchp, int c,
                                      float invM, const float* __restrict__ g,
                                      const float* __restrict__ b,
                                      float& sc, float& sh)
{
    float mean = acc[c] * invM;
    float var  = fmaxf(acc[nchp + c] * invM - mean * mean, 0.f);
    sc = g[c] * rsqrtf(var + EPS_);
    sh = b[c] - mean * sc;
}

// ---------------------------------------------------------------------------
// Zero the BN accumulator region (run first; harness poisons ws with 0xAA).
__global__ void k_zero(float* __restrict__ p, int n)
{
    int i = threadIdx.x;
    if (i < n) p[i] = 0.f;
}

// ---------------------------------------------------------------------------
// R5 GEMM structure (LDS-tiled, coalesced).
__device__ __forceinline__ void stage_x(const float* __restrict__ in,
                                        const float* __restrict__ ss,
                                        float* __restrict__ Xs, int row0, int t)
{
#pragma unroll
    for (int it = 0; it < 4; ++it) {
        int m = t + 256 * it;
        int r = m >> 4, j = m & 15;
        float4 v = ((const float4*)in)[(size_t)(row0 + r) * 16 + j];
        if (ss) {
            float4 sc = ((const float4*)ss)[j];
            float4 sh = ((const float4*)(ss + 64))[j];
            v.x = fmaxf(fmaf(v.x, sc.x, sh.x), 0.f);
            v.y = fmaxf(fmaf(v.y, sc.y, sh.y), 0.f);
            v.z = fmaxf(fmaf(v.z, sc.z, sh.z), 0.f);
            v.w = fmaxf(fmaf(v.w, sc.w, sh.w), 0.f);
        }
        *(float4*)&Xs[r * SW + 4 * j] = v;
    }
}

__device__ __forceinline__ void stage_w(const float* __restrict__ W,
                                        float* __restrict__ Ws, int t)
{
#pragma unroll
    for (int it = 0; it < 4; ++it) {
        int m = t + 256 * it;
        int r = m >> 4, j = m & 15;
        *(float4*)&Ws[r * SW + 4 * j] = ((const float4*)W)[m];
    }
}

__device__ __forceinline__ void compute_tile(const float* __restrict__ Xs,
                                             const float* __restrict__ Ws,
                                             int tx, int ty, float acc[4][4])
{
#pragma unroll
    for (int r = 0; r < 4; ++r)
#pragma unroll
        for (int c = 0; c < 4; ++c) acc[r][c] = 0.f;
    for (int kc = 0; kc < 16; ++kc) {
        float4 xf[4], wf[4];
#pragma unroll
        for (int r = 0; r < 4; ++r)
            xf[r] = *(const float4*)&Xs[(tx + 16 * r) * SW + 4 * kc];
#pragma unroll
        for (int c = 0; c < 4; ++c)
            wf[c] = *(const float4*)&Ws[(ty + 16 * c) * SW + 4 * kc];
#pragma unroll
        for (int r = 0; r < 4; ++r)
#pragma unroll
            for (int c = 0; c < 4; ++c) {
                acc[r][c] = fmaf(xf[r].x, wf[c].x, acc[r][c]);
                acc[r][c] = fmaf(xf[r].y, wf[c].y, acc[r][c]);
                acc[r][c] = fmaf(xf[r].z, wf[c].z, acc[r][c]);
                acc[r][c] = fmaf(xf[r].w, wf[c].w, acc[r][c]);
            }
    }
}

__device__ __forceinline__ void write_tile(float* __restrict__ buf, int tx, int ty,
                                           const float acc[4][4],
                                           const float* __restrict__ bias,
                                           float* __restrict__ out, int row0, int t)
{
    __syncthreads();
#pragma unroll
    for (int r = 0; r < 4; ++r)
#pragma unroll
        for (int c = 0; c < 4; ++c)
            buf[(tx + 16 * r) * SW + ty + 16 * c] = acc[r][c];
    __syncthreads();
#pragma unroll
    for (int it = 0; it < 4; ++it) {
        int m = t + 256 * it;
        int r = m >> 4, j = m & 15;
        float4 v = *(const float4*)&buf[r * SW + 4 * j];
        if (bias) {
            float4 bv = ((const float4*)bias)[j];
            v.x += bv.x; v.y += bv.y; v.z += bv.z; v.w += bv.w;
        }
        ((float4*)out)[(size_t)(row0 + r) * 16 + j] = v;
    }
    __syncthreads();
}

// bf16 variant: rounds to bf16 (RNE) and stores 8B/lane coalesced.
__device__ __forceinline__ void write_tile_bf16(float* __restrict__ buf, int tx, int ty,
                                                const float acc[4][4],
                                                const float* __restrict__ bias,
                                                unsigned short* __restrict__ out,
                                                int row0, int t)
{
    __syncthreads();
#pragma unroll
    for (int r = 0; r < 4; ++r)
#pragma unroll
        for (int c = 0; c < 4; ++c)
            buf[(tx + 16 * r) * SW + ty + 16 * c] = acc[r][c];
    __syncthreads();
#pragma unroll
    for (int it = 0; it < 4; ++it) {
        int m = t + 256 * it;
        int r = m >> 4, j = m & 15;
        float4 v = *(const float4*)&buf[r * SW + 4 * j];
        if (bias) {
            float4 bv = ((const float4*)bias)[j];
            v.x += bv.x; v.y += bv.y; v.z += bv.z; v.w += bv.w;
        }
        uint2 o;
        o.x = bf16_rne(v.x) | (bf16_rne(v.y) << 16);
        o.y = bf16_rne(v.z) | (bf16_rne(v.w) << 16);
        ((uint2*)out)[(size_t)(row0 + r) * 16 + j] = o;
    }
    __syncthreads();
}

// y = (optional relu(bn_from_acc(in))) @ W^T. BN params computed inline from
// raw acc sums (R11: no reducer kernel). Output column stats -> atomicAdd acc.
__global__ __launch_bounds__(256)
void k_gemm_tile(const float* __restrict__ in, const float* __restrict__ W,
                 const float* __restrict__ acc_in, const float* __restrict__ g_in,
                 const float* __restrict__ b_in, float invM_in,
                 float* __restrict__ out, float* __restrict__ acc_out)
{
    __shared__ float Xs[64 * SW];
    __shared__ float Ws[64 * SW];
    __shared__ float ssm[128];
    int t = threadIdx.x, tx = t & 15, ty = t >> 4;
    int row0 = blockIdx.x * 64;
    if (acc_in && t < 64) {
        float scv, shv;
        bn_ss(acc_in, 64, t, invM_in, g_in, b_in, scv, shv);
        ssm[t] = scv; ssm[64 + t] = shv;
    }
    __syncthreads();
    stage_x(in, acc_in ? ssm : nullptr, Xs, row0, t);
    stage_w(W, Ws, t);
    __syncthreads();
    float acc[4][4];
    compute_tile(Xs, Ws, tx, ty, acc);
    __syncthreads();
#pragma unroll
    for (int r = 0; r < 4; ++r)
#pragma unroll
        for (int c = 0; c < 4; ++c)
            Ws[(tx + 16 * r) * SW + ty + 16 * c] = acc[r][c];
    __syncthreads();
    float s0 = 0, s1 = 0, s2 = 0, s3 = 0, q0 = 0, q1 = 0, q2 = 0, q3 = 0;
#pragma unroll
    for (int it = 0; it < 4; ++it) {
        int m = t + 256 * it;
        int r = m >> 4, j = m & 15;
        float4 v = *(const float4*)&Ws[r * SW + 4 * j];
        ((float4*)out)[(size_t)(row0 + r) * 16 + j] = v;
        s0 += v.x; q0 = fmaf(v.x, v.x, q0);
        s1 += v.y; q1 = fmaf(v.y, v.y, q1);
        s2 += v.z; q2 = fmaf(v.z, v.z, q2);
        s3 += v.w; q3 = fmaf(v.w, v.w, q3);
    }
    float4* scr = (float4*)Xs;   // Xs dead after compute
    scr[t]       = make_float4(s0, s1, s2, s3);
    scr[256 + t] = make_float4(q0, q1, q2, q3);
    __syncthreads();
    if (t < 16) {   // thread t handles channels 4t..4t+3
        float4 S = make_float4(0, 0, 0, 0), Q = make_float4(0, 0, 0, 0);
#pragma unroll
        for (int k = 0; k < 16; ++k) {
            float4 a = scr[k * 16 + t], b = scr[256 + k * 16 + t];
            S.x += a.x; S.y += a.y; S.z += a.z; S.w += a.w;
            Q.x += b.x; Q.y += b.y; Q.z += b.z; Q.w += b.w;
        }
        atomicAdd(&acc_out[4 * t + 0], S.x); atomicAdd(&acc_out[4 * t + 1], S.y);
        atomicAdd(&acc_out[4 * t + 2], S.z); atomicAdd(&acc_out[4 * t + 3], S.w);
        atomicAdd(&acc_out[64 + 4 * t + 0], Q.x); atomicAdd(&acc_out[64 + 4 * t + 1], Q.y);
        atomicAdd(&acc_out[64 + 4 * t + 2], Q.z); atomicAdd(&acc_out[64 + 4 * t + 3], Q.w);
    }
}

// h = relu(bn1(y)) [bn1 inline from acc]; asrc16 = bf16(h@Wa^T+ba);
// adst = h@Wb^T+bb (f32); hw16 = bf16(h@Wc^T+bc)
__global__ __launch_bounds__(256)
void k_gemm3_tile(const float* __restrict__ y, const float* __restrict__ acc1,
                  const float* __restrict__ g1, const float* __restrict__ b1,
                  const float* __restrict__ Wa, const float* __restrict__ ba,
                  const float* __restrict__ Wb, const float* __restrict__ bb,
                  const float* __restrict__ Wc, const float* __restrict__ bc,
                  unsigned short* __restrict__ oa16, float* __restrict__ ob,
                  unsigned short* __restrict__ oc16)
{
    __shared__ float Xs[64 * SW];
    __shared__ float Ws[64 * SW];
    __shared__ float ssm[128];
    int t = threadIdx.x, tx = t & 15, ty = t >> 4;
    int row0 = blockIdx.x * 64;
    if (t < 64) {
        float scv, shv;
        bn_ss(acc1, 64, t, INV_N, g1, b1, scv, shv);
        ssm[t] = scv; ssm[64 + t] = shv;
    }
    __syncthreads();
    stage_x(y, ssm, Xs, row0, t);
    stage_w(Wa, Ws, t);
    __syncthreads();
    float acc[4][4];
    compute_tile(Xs, Ws, tx, ty, acc);
    write_tile_bf16(Ws, tx, ty, acc, ba, oa16, row0, t);
    stage_w(Wb, Ws, t);
    __syncthreads();
    compute_tile(Xs, Ws, tx, ty, acc);
    write_tile(Ws, tx, ty, acc, bb, ob, row0, t);
    stage_w(Wc, Ws, t);
    __syncthreads();
    compute_tile(Xs, Ws, tx, ty, acc);
    write_tile_bf16(Ws, tx, ty, acc, bc, oc16, row0, t);
}

// ---------------------------------------------------------------------------
// Stats of u = rel @ pos_w1^T + pos_b1 over E edges -> atomic acc (4+4).
__global__ __launch_bounds__(256)
void k_pos_stats(const float* __restrict__ pos, const int* __restrict__ src,
                 const float* __restrict__ pw1, const float* __restrict__ pb1,
                 float* __restrict__ acc)
{
    float s0 = 0, s1 = 0, s2 = 0, q0 = 0, q1 = 0, q2 = 0;
    int tid = blockIdx.x * 256 + threadIdx.x;
    for (int e = tid; e < E_; e += 1024 * 256) {
        int si = src[e], di = e >> 4;
        float rx = pos[3 * si + 0] - pos[3 * di + 0];
        float ry = pos[3 * si + 1] - pos[3 * di + 1];
        float rz = pos[3 * si + 2] - pos[3 * di + 2];
        float u0 = fmaf(rx, pw1[0], fmaf(ry, pw1[1], fmaf(rz, pw1[2], pb1[0])));
        float u1 = fmaf(rx, pw1[3], fmaf(ry, pw1[4], fmaf(rz, pw1[5], pb1[1])));
        float u2 = fmaf(rx, pw1[6], fmaf(ry, pw1[7], fmaf(rz, pw1[8], pb1[2])));
        s0 += u0; q0 = fmaf(u0, u0, q0);
        s1 += u1; q1 = fmaf(u1, u1, q1);
        s2 += u2; q2 = fmaf(u2, u2, q2);
    }
#pragma unroll
    for (int m = 1; m < 64; m <<= 1) {
        s0 += __shfl_xor(s0, m, 64); s1 += __shfl_xor(s1, m, 64); s2 += __shfl_xor(s2, m, 64);
        q0 += __shfl_xor(q0, m, 64); q1 += __shfl_xor(q1, m, 64); q2 += __shfl_xor(q2, m, 64);
    }
    __shared__ float red[4][8];
    int wv = threadIdx.x >> 6, ln = threadIdx.x & 63;
    if (ln == 0) {
        red[wv][0] = s0; red[wv][1] = s1; red[wv][2] = s2; red[wv][3] = 0.f;
        red[wv][4] = q0; red[wv][5] = q1; red[wv][6] = q2; red[wv][7] = 0.f;
    }
    __syncthreads();
    if (threadIdx.x < 8)
        atomicAdd(&acc[threadIdx.x],
                  red[0][threadIdx.x] + red[1][threadIdx.x] + red[2][threadIdx.x] + red[3][threadIdx.x]);
}

// ---------------------------------------------------------------------------
// R8 edge kernels (scalar math); R11: BN params inline from raw acc sums,
// block stats -> atomicAdd.

// Stats of a = bf16(a_src)[src]-a_dst[dst]+delta. Grid 2048 x 256.
__global__ __launch_bounds__(256)
void k_abn1_stats(const float* __restrict__ pos, const int* __restrict__ src,
                  const unsigned short* __restrict__ asrc16,
                  const float* __restrict__ adst,
                  const float* __restrict__ pw1, const float* __restrict__ pb1,
                  const float* __restrict__ accpos, const float* __restrict__ pbg,
                  const float* __restrict__ pbb, const float* __restrict__ pw2,
                  const float* __restrict__ pb2, float* __restrict__ acc_a1)
{
    int t = threadIdx.x;
    int l = t & 15, g = t >> 4, wv = t >> 6;
    int c0 = 4 * l;
    float ps0, ph0, ps1, ph1, ps2, ph2;
    bn_ss(accpos, 4, 0, INV_E, pbg, pbb, ps0, ph0);
    bn_ss(accpos, 4, 1, INV_E, pbg, pbb, ps1, ph1);
    bn_ss(accpos, 4, 2, INV_E, pbg, pbb, ps2, ph2);
    float4 p0 = *(const float4*)(pw2 + 12 * l);
    float4 p1 = *(const float4*)(pw2 + 12 * l + 4);
    float4 p2 = *(const float4*)(pw2 + 12 * l + 8);
    float4 pb = *(const float4*)(pb2 + c0);
    float sa0 = 0, sa1 = 0, sa2 = 0, sa3 = 0;
    float qa0 = 0, qa1 = 0, qa2 = 0, qa3 = 0;
#pragma unroll
    for (int nn = 0; nn < 2; ++nn) {
        int n = blockIdx.x * 32 + nn * 16 + g;
        float4 dv = *(const float4*)(adst + (size_t)n * 64 + c0);
        float pnx = pos[3 * n + 0], pny = pos[3 * n + 1], pnz = pos[3 * n + 2];
        int si_l = src[n * 16 + l];
        float rx = pos[3 * si_l + 0] - pnx;
        float ry = pos[3 * si_l + 1] - pny;
        float rz = pos[3 * si_l + 2] - pnz;
        float u0 = fmaf(rx, pw1[0], fmaf(ry, pw1[1], fmaf(rz, pw1[2], pb1[0])));
        float u1 = fmaf(rx, pw1[3], fmaf(ry, pw1[4], fmaf(rz, pw1[5], pb1[1])));
        float u2 = fmaf(rx, pw1[6], fmaf(ry, pw1[7], fmaf(rz, pw1[8], pb1[2])));
        float dl0 = fmaxf(fmaf(u0, ps0, ph0), 0.f);
        float dl1 = fmaxf(fmaf(u1, ps1, ph1), 0.f);
        float dl2 = fmaxf(fmaf(u2, ps2, ph2), 0.f);
        for (int k = 0; k < 16; ++k) {
            int si = __shfl(si_l, k, 16);
            float d0 = __shfl(dl0, k, 16);
            float d1 = __shfl(dl1, k, 16);
            float d2 = __shfl(dl2, k, 16);
            uint2 raw = ((const uint2*)asrc16)[(size_t)si * 16 + l];
            float avx = bf16_lo(raw.x), avy = bf16_hi(raw.x);
            float avz = bf16_lo(raw.y), avw = bf16_hi(raw.y);
            float del0 = fmaf(d0, p0.x, fmaf(d1, p0.y, fmaf(d2, p0.z, pb.x)));
            float del1 = fmaf(d0, p0.w, fmaf(d1, p1.x, fmaf(d2, p1.y, pb.y)));
            float del2 = fmaf(d0, p1.z, fmaf(d1, p1.w, fmaf(d2, p2.x, pb.z)));
            float del3 = fmaf(d0, p2.y, fmaf(d1, p2.z, fmaf(d2, p2.w, pb.w)));
            float a0 = avx - dv.x + del0;
            float a1 = avy - dv.y + del1;
            float a2 = avz - dv.z + del2;
            float a3 = avw - dv.w + del3;
            sa0 += a0; qa0 = fmaf(a0, a0, qa0);
            sa1 += a1; qa1 = fmaf(a1, a1, qa1);
            sa2 += a2; qa2 = fmaf(a2, a2, qa2);
            sa3 += a3; qa3 = fmaf(a3, a3, qa3);
        }
    }
#pragma unroll
    for (int m = 16; m <= 32; m <<= 1) {
        sa0 += __shfl_xor(sa0, m, 64); sa1 += __shfl_xor(sa1, m, 64);
        sa2 += __shfl_xor(sa2, m, 64); sa3 += __shfl_xor(sa3, m, 64);
        qa0 += __shfl_xor(qa0, m, 64); qa1 += __shfl_xor(qa1, m, 64);
        qa2 += __shfl_xor(qa2, m, 64); qa3 += __shfl_xor(qa3, m, 64);
    }
    __shared__ float red[4][128];
    if ((t & 63) < 16) {
        red[wv][c0 + 0] = sa0; red[wv][c0 + 1] = sa1;
        red[wv][c0 + 2] = sa2; red[wv][c0 + 3] = sa3;
        red[wv][64 + c0 + 0] = qa0; red[wv][64 + c0 + 1] = qa1;
        red[wv][64 + c0 + 2] = qa2; red[wv][64 + c0 + 3] = qa3;
    }
    __syncthreads();
    if (t < 128)
        atomicAdd(&acc_a1[t], red[0][t] + red[1][t] + red[2][t] + red[3][t]);
}

// ---------------------------------------------------------------------------
// t1 = relu(abn1(a)) @ attn_w1^T + attn_b1; abn2 stats -> atomics. 2048 x 256.
__global__ __launch_bounds__(256)
void k_edge_t1(const float* __restrict__ pos, const int* __restrict__ src,
               const unsigned short* __restrict__ asrc16,
               const float* __restrict__ adst,
               const float* __restrict__ pw1, const float* __restrict__ pb1,
               const float* __restrict__ accpos, const float* __restrict__ pbg,
               const float* __restrict__ pbb, const float* __restrict__ pw2,
               const float* __restrict__ pb2, const float* __restrict__ acc_a1,
               const float* __restrict__ a1g, const float* __restrict__ a1b,
               const float* __restrict__ aw1, const float* __restrict__ ab1,
               float* __restrict__ t1, float* __restrict__ acc_a2)
{
    int t = threadIdx.x;
    int l = t & 15, g = t >> 4, wv = t >> 6;
    int c0 = 4 * l;
    int ch = 4 * (l & 1) + 2 * ((l >> 1) & 1) + ((l >> 2) & 1);
    float abv = ab1[ch];
    float ps0, ph0, ps1, ph1, ps2, ph2;
    bn_ss(accpos, 4, 0, INV_E, pbg, pbb, ps0, ph0);
    bn_ss(accpos, 4, 1, INV_E, pbg, pbb, ps1, ph1);
    bn_ss(accpos, 4, 2, INV_E, pbg, pbb, ps2, ph2);
    float scx, shx, scy, shy, scz, shz, scw, shw;
    bn_ss(acc_a1, 64, c0 + 0, INV_E, a1g, a1b, scx, shx);
    bn_ss(acc_a1, 64, c0 + 1, INV_E, a1g, a1b, scy, shy);
    bn_ss(acc_a1, 64, c0 + 2, INV_E, a1g, a1b, scz, shz);
    bn_ss(acc_a1, 64, c0 + 3, INV_E, a1g, a1b, scw, shw);
    float4 p0 = *(const float4*)(pw2 + 12 * l);
    float4 p1 = *(const float4*)(pw2 + 12 * l + 4);
    float4 p2 = *(const float4*)(pw2 + 12 * l + 8);
    float4 pb = *(const float4*)(pb2 + c0);
    float4 w1[8];
#pragma unroll
    for (int jj = 0; jj < 8; ++jj) w1[jj] = *(const float4*)(aw1 + jj * 64 + c0);
    float sse = 0.f, ssq = 0.f;
#pragma unroll
    for (int nn = 0; nn < 2; ++nn) {
        int n = blockIdx.x * 32 + nn * 16 + g;
        float4 dv = *(const float4*)(adst + (size_t)n * 64 + c0);
        float pnx = pos[3 * n + 0], pny = pos[3 * n + 1], pnz = pos[3 * n + 2];
        int si_l = src[n * 16 + l];
        float rx = pos[3 * si_l + 0] - pnx;
        float ry = pos[3 * si_l + 1] - pny;
        float rz = pos[3 * si_l + 2] - pnz;
        float u0 = fmaf(rx, pw1[0], fmaf(ry, pw1[1], fmaf(rz, pw1[2], pb1[0])));
        float u1 = fmaf(rx, pw1[3], fmaf(ry, pw1[4], fmaf(rz, pw1[5], pb1[1])));
        float u2 = fmaf(rx, pw1[6], fmaf(ry, pw1[7], fmaf(rz, pw1[8], pb1[2])));
        float dl0 = fmaxf(fmaf(u0, ps0, ph0), 0.f);
        float dl1 = fmaxf(fmaf(u1, ps1, ph1), 0.f);
        float dl2 = fmaxf(fmaf(u2, ps2, ph2), 0.f);
        for (int k = 0; k < 16; ++k) {
            int si = __shfl(si_l, k, 16);
            float d0 = __shfl(dl0, k, 16);
            float d1 = __shfl(dl1, k, 16);
            float d2 = __shfl(dl2, k, 16);
            uint2 raw = ((const uint2*)asrc16)[(size_t)si * 16 + l];
            float avx = bf16_lo(raw.x), avy = bf16_hi(raw.x);
            float avz = bf16_lo(raw.y), avw = bf16_hi(raw.y);
            float del0 = fmaf(d0, p0.x, fmaf(d1, p0.y, fmaf(d2, p0.z, pb.x)));
            float del1 = fmaf(d0, p0.w, fmaf(d1, p1.x, fmaf(d2, p1.y, pb.y)));
            float del2 = fmaf(d0, p1.z, fmaf(d1, p1.w, fmaf(d2, p2.x, pb.z)));
            float del3 = fmaf(d0, p2.y, fmaf(d1, p2.z, fmaf(d2, p2.w, pb.w)));
            float an0 = fmaxf(fmaf(avx - dv.x + del0, scx, shx), 0.f);
            float an1 = fmaxf(fmaf(avy - dv.y + del1, scy, shy), 0.f);
            float an2 = fmaxf(fmaf(avz - dv.z + del2, scz, shz), 0.f);
            float an3 = fmaxf(fmaf(avw - dv.w + del3, scw, shw), 0.f);
            float tp[8];
#pragma unroll
            for (int jj = 0; jj < 8; ++jj)
                tp[jj] = fmaf(an0, w1[jj].x, fmaf(an1, w1[jj].y,
                         fmaf(an2, w1[jj].z, an3 * w1[jj].w)));
            // reduce-scatter: 8 -> 4 -> 2 -> 1 values
            float s4[4];
#pragma unroll
            for (int j = 0; j < 4; ++j) {
                float send = (l & 1) ? tp[j] : tp[j + 4];
                float recv = __shfl_xor(send, 1, 64);
                s4[j] = ((l & 1) ? tp[j + 4] : tp[j]) + recv;
            }
            float s2[2];
#pragma unroll
            for (int j = 0; j < 2; ++j) {
                float send = (l & 2) ? s4[j] : s4[j + 2];
                float recv = __shfl_xor(send, 2, 64);
                s2[j] = ((l & 2) ? s4[j + 2] : s4[j]) + recv;
            }
            float send = (l & 4) ? s2[0] : s2[1];
            float recv = __shfl_xor(send, 4, 64);
            float s1 = ((l & 4) ? s2[1] : s2[0]) + recv;
            s1 += __shfl_xor(s1, 8, 64);
            float o = s1 + abv;
            if (l < 8) t1[(size_t)(n * 16 + k) * 8 + ch] = o;
            sse += o; ssq = fmaf(o, o, ssq);
        }
    }
#pragma unroll
    for (int m = 16; m <= 32; m <<= 1) {
        sse += __shfl_xor(sse, m, 64);
        ssq += __shfl_xor(ssq, m, 64);
    }
    __shared__ float red[4][16];
    if ((t & 63) < 8) { red[wv][ch] = sse; red[wv][8 + ch] = ssq; }
    __syncthreads();
    if (t < 16)
        atomicAdd(&acc_a2[t], red[0][t] + red[1][t] + red[2][t] + red[3][t]);
}

// ---------------------------------------------------------------------------
// Softmax + weighted aggregate, group-per-node; bn2 stats -> atomics.
// Grid 4096 x 256 (16 nodes/blk).
__global__ __launch_bounds__(256)
void k_node_aggr(const float* __restrict__ pos, const int* __restrict__ src,
                 const float* __restrict__ t1, const float* __restrict__ acc_a2,
                 const float* __restrict__ a2g, const float* __restrict__ a2b,
                 const float* __restrict__ aw2, const float* __restrict__ ab2,
                 const unsigned short* __restrict__ hw16,
                 const float* __restrict__ accpos, const float* __restrict__ pbg,
                 const float* __restrict__ pbb,
                 const float* __restrict__ pw1, const float* __restrict__ pb1,
                 const float* __restrict__ pw2, const float* __restrict__ pb2,
                 float* __restrict__ out, float* __restrict__ acc_bn2)
{
    __shared__ float alds[16][196];   // [group][k*12 + ch8]; later stats scratch
    __shared__ float ssm2[16];
    int t = threadIdx.x, l = t & 15, g = t >> 4;
    int c0 = 4 * l;
    if (t < 8) {
        float scv, shv;
        bn_ss(acc_a2, 8, t, INV_E, a2g, a2b, scv, shv);
        ssm2[t] = scv; ssm2[8 + t] = shv;
    }
    __syncthreads();
    float ps0, ph0, ps1, ph1, ps2, ph2;
    bn_ss(accpos, 4, 0, INV_E, pbg, pbb, ps0, ph0);
    bn_ss(accpos, 4, 1, INV_E, pbg, pbb, ps1, ph1);
    bn_ss(accpos, 4, 2, INV_E, pbg, pbb, ps2, ph2);
    float4 p0 = *(const float4*)(pw2 + 12 * l);
    float4 p1 = *(const float4*)(pw2 + 12 * l + 4);
    float4 p2 = *(const float4*)(pw2 + 12 * l + 8);
    float4 pb = *(const float4*)(pb2 + c0);
    int alof = (l & 1) * 4;
    int n = blockIdx.x * 16 + g;
    int e = n * 16 + l;
    // ---- phase A: per-edge attention logits + softmax over the group
    const float4* t4 = (const float4*)(t1 + (size_t)e * 8);
    float4 ta = t4[0], tb = t4[1];
    float tv[8] = {ta.x, ta.y, ta.z, ta.w, tb.x, tb.y, tb.z, tb.w};
    float tn[8];
#pragma unroll
    for (int j = 0; j < 8; ++j)
        tn[j] = fmaxf(fmaf(tv[j], ssm2[j], ssm2[8 + j]), 0.f);
    float al[8];
#pragma unroll
    for (int j = 0; j < 8; ++j) {
        float acc = ab2[j];
#pragma unroll
        for (int i = 0; i < 8; ++i) acc = fmaf(tn[i], aw2[j * 8 + i], acc);
        float m = acc;
#pragma unroll
        for (int msk = 1; msk < 16; msk <<= 1) m = fmaxf(m, __shfl_xor(m, msk, 64));
        float ex = __expf(acc - m);
        float sm = ex;
#pragma unroll
        for (int msk = 1; msk < 16; msk <<= 1) sm += __shfl_xor(sm, msk, 64);
        al[j] = ex / sm;
    }
    *(float4*)&alds[g][l * 12]     = make_float4(al[0], al[1], al[2], al[3]);
    *(float4*)&alds[g][l * 12 + 4] = make_float4(al[4], al[5], al[6], al[7]);
    int silane = src[e];
    float pnx = pos[3 * n + 0], pny = pos[3 * n + 1], pnz = pos[3 * n + 2];
    // own-edge d
    float rx = pos[3 * silane + 0] - pnx;
    float ry = pos[3 * silane + 1] - pny;
    float rz = pos[3 * silane + 2] - pnz;
    float u0 = fmaf(rx, pw1[0], fmaf(ry, pw1[1], fmaf(rz, pw1[2], pb1[0])));
    float u1 = fmaf(rx, pw1[3], fmaf(ry, pw1[4], fmaf(rz, pw1[5], pb1[1])));
    float u2 = fmaf(rx, pw1[6], fmaf(ry, pw1[7], fmaf(rz, pw1[8], pb1[2])));
    float dl0 = fmaxf(fmaf(u0, ps0, ph0), 0.f);
    float dl1 = fmaxf(fmaf(u1, ps1, ph1), 0.f);
    float dl2 = fmaxf(fmaf(u2, ps2, ph2), 0.f);
    // ---- phase B: accumulate own 4 channels over the node's 16 edges
    float a0 = 0.f, a1 = 0.f, a2 = 0.f, a3 = 0.f;
#pragma unroll 4
    for (int k = 0; k < 16; ++k) {
        int sk = __shfl(silane, k, 16);
        float d0 = __shfl(dl0, k, 16);
        float d1 = __shfl(dl1, k, 16);
        float d2 = __shfl(dl2, k, 16);
        uint2 raw = ((const uint2*)hw16)[(size_t)sk * 16 + l];
        float hvx = bf16_lo(raw.x), hvy = bf16_hi(raw.x);
        float hvz = bf16_lo(raw.y), hvw = bf16_hi(raw.y);
        float4 alv = *(const float4*)&alds[g][k * 12 + alof];
        float del0 = fmaf(d0, p0.x, fmaf(d1, p0.y, fmaf(d2, p0.z, pb.x)));
        float del1 = fmaf(d0, p0.w, fmaf(d1, p1.x, fmaf(d2, p1.y, pb.y)));
        float del2 = fmaf(d0, p1.z, fmaf(d1, p1.w, fmaf(d2, p2.x, pb.z)));
        float del3 = fmaf(d0, p2.y, fmaf(d1, p2.z, fmaf(d2, p2.w, pb.w)));
        a0 = fmaf(alv.x, hvx + del0, a0);
        a1 = fmaf(alv.y, hvy + del1, a1);
        a2 = fmaf(alv.z, hvz + del2, a2);
        a3 = fmaf(alv.w, hvw + del3, a3);
    }
    *(float4*)(out + (size_t)n * 64 + c0) = make_float4(a0, a1, a2, a3);
    // ---- bn2 stats: reduce over the block's 16 nodes per channel
    __syncthreads();   // all alds reads done
    float4* scr = (float4*)&alds[0][0];   // 512 float4 <= 3136 floats OK
    scr[g * 16 + l]       = make_float4(a0, a1, a2, a3);
    scr[256 + g * 16 + l] = make_float4(a0 * a0, a1 * a1, a2 * a2, a3 * a3);
    __syncthreads();
    if (t < 16) {   // thread t handles channels 4t..4t+3
        float4 S = make_float4(0, 0, 0, 0), Q = make_float4(0, 0, 0, 0);
#pragma unroll
        for (int k = 0; k < 16; ++k) {
            float4 a = scr[k * 16 + t], b = scr[256 + k * 16 + t];
            S.x += a.x; S.y += a.y; S.z += a.z; S.w += a.w;
            Q.x += b.x; Q.y += b.y; Q.z += b.z; Q.w += b.w;
        }
        atomicAdd(&acc_bn2[4 * t + 0], S.x); atomicAdd(&acc_bn2[4 * t + 1], S.y);
        atomicAdd(&acc_bn2[4 * t + 2], S.z); atomicAdd(&acc_bn2[4 * t + 3], S.w);
        atomicAdd(&acc_bn2[64 + 4 * t + 0], Q.x); atomicAdd(&acc_bn2[64 + 4 * t + 1], Q.y);
        atomicAdd(&acc_bn2[64 + 4 * t + 2], Q.z); atomicAdd(&acc_bn2[64 + 4 * t + 3], Q.w);
    }
}

// ---------------------------------------------------------------------------
// out = relu(bn3(y3) + x_skip); bn3 params inline from acc.
__global__ __launch_bounds__(256)
void k_final(const float* __restrict__ y3, const float* __restrict__ acc3,
             const float* __restrict__ g3, const float* __restrict__ b3,
             const float* __restrict__ x, float* __restrict__ out)
{
    int i = blockIdx.x * 256 + threadIdx.x;   // float4 index
    int c4 = i & 15;
    float scx, shx, scy, shy, scz, shz, scw, shw;
    bn_ss(acc3, 64, 4 * c4 + 0, INV_N, g3, b3, scx, shx);
    bn_ss(acc3, 64, 4 * c4 + 1, INV_N, g3, b3, scy, shy);
    bn_ss(acc3, 64, 4 * c4 + 2, INV_N, g3, b3, scz, shz);
    bn_ss(acc3, 64, 4 * c4 + 3, INV_N, g3, b3, scw, shw);
    float4 v  = ((const float4*)y3)[i];
    float4 xs = ((const float4*)x)[i];
    float4 o;
    o.x = fmaxf(fmaf(v.x, scx, shx) + xs.x, 0.f);
    o.y = fmaxf(fmaf(v.y, scy, shy) + xs.y, 0.f);
    o.z = fmaxf(fmaf(v.z, scz, shz) + xs.z, 0.f);
    o.w = fmaxf(fmaf(v.w, scw, shw) + xs.w, 0.f);
    ((float4*)out)[i] = o;
}

// ---------------------------------------------------------------------------
extern "C" void kernel_launch(void* const* d_in, const int* in_sizes, int n_in,
                              void* d_out, int out_size, void* d_ws, size_t ws_size,
                              hipStream_t stream)
{
    const float* x    = (const float*)d_in[0];
    const float* pos  = (const float*)d_in[1];
    const int*   src  = (const int*)d_in[2];           // edge_index row 0
    const float* W_in = (const float*)d_in[3];
    const float* W_out= (const float*)d_in[4];
    const float* pw1  = (const float*)d_in[5];
    const float* pb1  = (const float*)d_in[6];
    const float* pbg  = (const float*)d_in[7];
    const float* pbb  = (const float*)d_in[8];
    const float* pw2  = (const float*)d_in[9];
    const float* pb2  = (const float*)d_in[10];
    const float* a1g  = (const float*)d_in[11];
    const float* a1b  = (const float*)d_in[12];
    const float* aw1  = (const float*)d_in[13];
    const float* ab1  = (const float*)d_in[14];
    const float* a2g  = (const float*)d_in[15];
    const float* a2b  = (const float*)d_in[16];
    const float* aw2  = (const float*)d_in[17];
    const float* ab2  = (const float*)d_in[18];
    const float* linw = (const float*)d_in[19];
    const float* linb = (const float*)d_in[20];
    const float* srcw = (const float*)d_in[21];
    const float* srcb = (const float*)d_in[22];
    const float* dstw = (const float*)d_in[23];
    const float* dstb = (const float*)d_in[24];
    const float* bn1g = (const float*)d_in[25];
    const float* bn1b = (const float*)d_in[26];
    const float* bn2g = (const float*)d_in[27];
    const float* bn2b = (const float*)d_in[28];
    const float* bn3g = (const float*)d_in[29];
    const float* bn3b = (const float*)d_in[30];
    float* outp = (float*)d_out;

    float* ws = (float*)d_ws;
    const size_t NC = (size_t)N_ * C_;
    float* buf_y     = ws;                       // y1, later y3
    float* buf_adst  = ws + NC;                  // a_dst f32; later reused as out
    unsigned short* asrc16 = (unsigned short*)(ws + 2 * NC);       // NC/2 floats
    unsigned short* hw16   = (unsigned short*)(ws + 2 * NC + NC / 2);
    float* buf_t1    = ws + 3 * NC;              // [E,8] f32
    float* accb      = ws + 3 * NC + (size_t)E_ * 8;
    float* acc_bn1 = accb;         // 128: [sum 64][sumsq 64]
    float* acc_pos = accb + 128;   // 8
    float* acc_a1  = accb + 136;   // 128
    float* acc_a2  = accb + 264;   // 16
    float* acc_bn2 = accb + 280;   // 128
    float* acc_bn3 = accb + 408;   // 128  (total 536)
    // buf_out aliases buf_adst: adst last read by k_edge_t1.
    float* buf_out = buf_adst;

    // 0) zero BN accumulators
    k_zero<<<1, 1024, 0, stream>>>(accb, 536);
    // 1) y1 = x @ W_in^T (+ atomic bn1 stats)
    k_gemm_tile<<<1024, 256, 0, stream>>>(x, W_in, nullptr, nullptr, nullptr, 0.f,
                                          buf_y, acc_bn1);
    // 2) h = relu(bn1(y1)); asrc16 (bf16) / adst (f32) / hw16 (bf16)
    k_gemm3_tile<<<1024, 256, 0, stream>>>(buf_y, acc_bn1, bn1g, bn1b,
                                           srcw, srcb, dstw, dstb, linw, linb,
                                           asrc16, buf_adst, hw16);
    // 3) pos-BN stats (atomic)
    k_pos_stats<<<1024, 256, 0, stream>>>(pos, src, pw1, pb1, acc_pos);
    // 4) attn_bn1 stats (atomic)
    k_abn1_stats<<<2048, 256, 0, stream>>>(pos, src, asrc16, buf_adst,
                                           pw1, pb1, acc_pos, pbg, pbb,
                                           pw2, pb2, acc_a1);
    // 5) t1 + abn2 stats (atomic)
    k_edge_t1<<<2048, 256, 0, stream>>>(pos, src, asrc16, buf_adst,
                                        pw1, pb1, acc_pos, pbg, pbb, pw2, pb2,
                                        acc_a1, a1g, a1b, aw1, ab1,
                                        buf_t1, acc_a2);
    // 6) softmax + weighted aggregate -> out (+ atomic bn2 stats)
    k_node_aggr<<<4096, 256, 0, stream>>>(pos, src, buf_t1, acc_a2, a2g, a2b,
                                          aw2, ab2, hw16, acc_pos, pbg, pbb,
                                          pw1, pb1, pw2, pb2, buf_out, acc_bn2);
    // 7) y3 = relu(bn2(out)) @ W_out^T (+ atomic bn3 stats)
    k_gemm_tile<<<1024, 256, 0, stream>>>(buf_out, W_out, acc_bn2, bn2g, bn2b, INV_N,
                                          buf_y, acc_bn3);
    // 8) out = relu(bn3(y3) + x)
    k_final<<<(N_ * C_ / 4) / 256, 256, 0, stream>>>(buf_y, acc_bn3, bn3g, bn3b, x, outp);

    (void)in_sizes; (void)n_in; (void)out_size; (void)ws_size;
}

// Round 12
// 328.001 us; speedup vs baseline: 3.4441x; 3.4441x over previous
//
#include <hip/hip_runtime.h>
#include <cstddef>

constexpr int N_ = 65536;
constexpr int K_ = 16;
constexpr int E_ = N_ * K_;      // 1048576
constexpr int C_ = 64;
#define EPS_ 1e-5f
#define SW 68   // LDS row stride (words) for GEMM tiles
#define INV_N (1.f / 65536.f)
#define INV_E (1.f / 1048576.f)
#define NSLOT 64   // atomic-contention spread (R11 post-mortem: 4 lines -> 534us)

typedef unsigned int uint_t;

// bf16 helpers (RNE pack, cheap unpack)
__device__ __forceinline__ uint_t bf16_rne(float f) {
    uint_t u = __float_as_uint(f);
    return (u + 0x7fffu + ((u >> 16) & 1u)) >> 16;
}
__device__ __forceinline__ float bf16_lo(uint_t p) { return __uint_as_float(p << 16); }
__device__ __forceinline__ float bf16_hi(uint_t p) { return __uint_as_float(p & 0xffff0000u); }

// scale/shift from raw summed {sum, sumsq}: s[c]=sum, s[nchp+c]=sumsq
__device__ __forceinline__ void bn_ss(const float* __restrict__ s, int nchp, int c,
                                      float invM, const float* __restrict__ g,
                                      const float* __restrict__ b,
                                      float& sc, float& sh)
{
    float mean = s[c] * invM;
    float var  = fmaxf(s[nchp + c] * invM - mean * mean, 0.f);
    sc = g[c] * rsqrtf(var + EPS_);
    sh = b[c] - mean * sc;
}

// ---------------------------------------------------------------------------
// Zero the BN accumulator region (harness poisons ws with 0xAA).
__global__ void k_zero(float* __restrict__ p, int n)
{
    int i = blockIdx.x * 1024 + threadIdx.x;
    if (i < n) p[i] = 0.f;
}

// ---------------------------------------------------------------------------
// R5 GEMM structure (LDS-tiled, coalesced).
__device__ __forceinline__ void stage_x(const float* __restrict__ in,
                                        const float* __restrict__ ss,
                                        float* __restrict__ Xs, int row0, int t)
{
#pragma unroll
    for (int it = 0; it < 4; ++it) {
        int m = t + 256 * it;
        int r = m >> 4, j = m & 15;
        float4 v = ((const float4*)in)[(size_t)(row0 + r) * 16 + j];
        if (ss) {
            float4 sc = ((const float4*)ss)[j];
            float4 sh = ((const float4*)(ss + 64))[j];
            v.x = fmaxf(fmaf(v.x, sc.x, sh.x), 0.f);
            v.y = fmaxf(fmaf(v.y, sc.y, sh.y), 0.f);
            v.z = fmaxf(fmaf(v.z, sc.z, sh.z), 0.f);
            v.w = fmaxf(fmaf(v.w, sc.w, sh.w), 0.f);
        }
        *(float4*)&Xs[r * SW + 4 * j] = v;
    }
}

__device__ __forceinline__ void stage_w(const float* __restrict__ W,
                                        float* __restrict__ Ws, int t)
{
#pragma unroll
    for (int it = 0; it < 4; ++it) {
        int m = t + 256 * it;
        int r = m >> 4, j = m & 15;
        *(float4*)&Ws[r * SW + 4 * j] = ((const float4*)W)[m];
    }
}

__device__ __forceinline__ void compute_tile(const float* __restrict__ Xs,
                                             const float* __restrict__ Ws,
                                             int tx, int ty, float acc[4][4])
{
#pragma unroll
    for (int r = 0; r < 4; ++r)
#pragma unroll
        for (int c = 0; c < 4; ++c) acc[r][c] = 0.f;
    for (int kc = 0; kc < 16; ++kc) {
        float4 xf[4], wf[4];
#pragma unroll
        for (int r = 0; r < 4; ++r)
            xf[r] = *(const float4*)&Xs[(tx + 16 * r) * SW + 4 * kc];
#pragma unroll
        for (int c = 0; c < 4; ++c)
            wf[c] = *(const float4*)&Ws[(ty + 16 * c) * SW + 4 * kc];
#pragma unroll
        for (int r = 0; r < 4; ++r)
#pragma unroll
            for (int c = 0; c < 4; ++c) {
                acc[r][c] = fmaf(xf[r].x, wf[c].x, acc[r][c]);
                acc[r][c] = fmaf(xf[r].y, wf[c].y, acc[r][c]);
                acc[r][c] = fmaf(xf[r].z, wf[c].z, acc[r][c]);
                acc[r][c] = fmaf(xf[r].w, wf[c].w, acc[r][c]);
            }
    }
}

__device__ __forceinline__ void write_tile(float* __restrict__ buf, int tx, int ty,
                                           const float acc[4][4],
                                           const float* __restrict__ bias,
                                           float* __restrict__ out, int row0, int t)
{
    __syncthreads();
#pragma unroll
    for (int r = 0; r < 4; ++r)
#pragma unroll
        for (int c = 0; c < 4; ++c)
            buf[(tx + 16 * r) * SW + ty + 16 * c] = acc[r][c];
    __syncthreads();
#pragma unroll
    for (int it = 0; it < 4; ++it) {
        int m = t + 256 * it;
        int r = m >> 4, j = m & 15;
        float4 v = *(const float4*)&buf[r * SW + 4 * j];
        if (bias) {
            float4 bv = ((const float4*)bias)[j];
            v.x += bv.x; v.y += bv.y; v.z += bv.z; v.w += bv.w;
        }
        ((float4*)out)[(size_t)(row0 + r) * 16 + j] = v;
    }
    __syncthreads();
}

// bf16 variant: rounds to bf16 (RNE) and stores 8B/lane coalesced.
__device__ __forceinline__ void write_tile_bf16(float* __restrict__ buf, int tx, int ty,
                                                const float acc[4][4],
                                                const float* __restrict__ bias,
                                                unsigned short* __restrict__ out,
                                                int row0, int t)
{
    __syncthreads();
#pragma unroll
    for (int r = 0; r < 4; ++r)
#pragma unroll
        for (int c = 0; c < 4; ++c)
            buf[(tx + 16 * r) * SW + ty + 16 * c] = acc[r][c];
    __syncthreads();
#pragma unroll
    for (int it = 0; it < 4; ++it) {
        int m = t + 256 * it;
        int r = m >> 4, j = m & 15;
        float4 v = *(const float4*)&buf[r * SW + 4 * j];
        if (bias) {
            float4 bv = ((const float4*)bias)[j];
            v.x += bv.x; v.y += bv.y; v.z += bv.z; v.w += bv.w;
        }
        uint2 o;
        o.x = bf16_rne(v.x) | (bf16_rne(v.y) << 16);
        o.y = bf16_rne(v.z) | (bf16_rne(v.w) << 16);
        ((uint2*)out)[(size_t)(row0 + r) * 16 + j] = o;
    }
    __syncthreads();
}

// y = (optional relu(bn_from_slots(in))) @ W^T. BN params summed+computed
// inline; output column stats -> slot-spread atomicAdd.
__global__ __launch_bounds__(256)
void k_gemm_tile(const float* __restrict__ in, const float* __restrict__ W,
                 const float* __restrict__ acc_in, const float* __restrict__ g_in,
                 const float* __restrict__ b_in, float invM_in,
                 float* __restrict__ out, float* __restrict__ acc_out)
{
    __shared__ float Xs[64 * SW];
    __shared__ float Ws[64 * SW];
    __shared__ float ssm[128];
    __shared__ float raws[128];
    int t = threadIdx.x, tx = t & 15, ty = t >> 4;
    int row0 = blockIdx.x * 64;
    if (acc_in) {
        if (t < 128) {
            float s = 0.f;
            for (int sl = 0; sl < NSLOT; ++sl) s += acc_in[sl * 128 + t];
            raws[t] = s;
        }
        __syncthreads();
        if (t < 64) {
            float scv, shv;
            bn_ss(raws, 64, t, invM_in, g_in, b_in, scv, shv);
            ssm[t] = scv; ssm[64 + t] = shv;
        }
    }
    __syncthreads();
    stage_x(in, acc_in ? ssm : nullptr, Xs, row0, t);
    stage_w(W, Ws, t);
    __syncthreads();
    float acc[4][4];
    compute_tile(Xs, Ws, tx, ty, acc);
    __syncthreads();
#pragma unroll
    for (int r = 0; r < 4; ++r)
#pragma unroll
        for (int c = 0; c < 4; ++c)
            Ws[(tx + 16 * r) * SW + ty + 16 * c] = acc[r][c];
    __syncthreads();
    float s0 = 0, s1 = 0, s2 = 0, s3 = 0, q0 = 0, q1 = 0, q2 = 0, q3 = 0;
#pragma unroll
    for (int it = 0; it < 4; ++it) {
        int m = t + 256 * it;
        int r = m >> 4, j = m & 15;
        float4 v = *(const float4*)&Ws[r * SW + 4 * j];
        ((float4*)out)[(size_t)(row0 + r) * 16 + j] = v;
        s0 += v.x; q0 = fmaf(v.x, v.x, q0);
        s1 += v.y; q1 = fmaf(v.y, v.y, q1);
        s2 += v.z; q2 = fmaf(v.z, v.z, q2);
        s3 += v.w; q3 = fmaf(v.w, v.w, q3);
    }
    float4* scr = (float4*)Xs;   // Xs dead after compute
    scr[t]       = make_float4(s0, s1, s2, s3);
    scr[256 + t] = make_float4(q0, q1, q2, q3);
    __syncthreads();
    if (t < 16) {   // thread t handles channels 4t..4t+3
        float4 S = make_float4(0, 0, 0, 0), Q = make_float4(0, 0, 0, 0);
#pragma unroll
        for (int k = 0; k < 16; ++k) {
            float4 a = scr[k * 16 + t], b = scr[256 + k * 16 + t];
            S.x += a.x; S.y += a.y; S.z += a.z; S.w += a.w;
            Q.x += b.x; Q.y += b.y; Q.z += b.z; Q.w += b.w;
        }
        float* ao = acc_out + (blockIdx.x & (NSLOT - 1)) * 128;
        atomicAdd(&ao[4 * t + 0], S.x); atomicAdd(&ao[4 * t + 1], S.y);
        atomicAdd(&ao[4 * t + 2], S.z); atomicAdd(&ao[4 * t + 3], S.w);
        atomicAdd(&ao[64 + 4 * t + 0], Q.x); atomicAdd(&ao[64 + 4 * t + 1], Q.y);
        atomicAdd(&ao[64 + 4 * t + 2], Q.z); atomicAdd(&ao[64 + 4 * t + 3], Q.w);
    }
}

// h = relu(bn1(y)) [bn1 from slots]; asrc16 = bf16(h@Wa^T+ba);
// adst = h@Wb^T+bb (f32); hw16 = bf16(h@Wc^T+bc)
__global__ __launch_bounds__(256)
void k_gemm3_tile(const float* __restrict__ y, const float* __restrict__ acc1,
                  const float* __restrict__ g1, const float* __restrict__ b1,
                  const float* __restrict__ Wa, const float* __restrict__ ba,
                  const float* __restrict__ Wb, const float* __restrict__ bb,
                  const float* __restrict__ Wc, const float* __restrict__ bc,
                  unsigned short* __restrict__ oa16, float* __restrict__ ob,
                  unsigned short* __restrict__ oc16)
{
    __shared__ float Xs[64 * SW];
    __shared__ float Ws[64 * SW];
    __shared__ float ssm[128];
    __shared__ float raws[128];
    int t = threadIdx.x, tx = t & 15, ty = t >> 4;
    int row0 = blockIdx.x * 64;
    if (t < 128) {
        float s = 0.f;
        for (int sl = 0; sl < NSLOT; ++sl) s += acc1[sl * 128 + t];
        raws[t] = s;
    }
    __syncthreads();
    if (t < 64) {
        float scv, shv;
        bn_ss(raws, 64, t, INV_N, g1, b1, scv, shv);
        ssm[t] = scv; ssm[64 + t] = shv;
    }
    __syncthreads();
    stage_x(y, ssm, Xs, row0, t);
    stage_w(Wa, Ws, t);
    __syncthreads();
    float acc[4][4];
    compute_tile(Xs, Ws, tx, ty, acc);
    write_tile_bf16(Ws, tx, ty, acc, ba, oa16, row0, t);
    stage_w(Wb, Ws, t);
    __syncthreads();
    compute_tile(Xs, Ws, tx, ty, acc);
    write_tile(Ws, tx, ty, acc, bb, ob, row0, t);
    stage_w(Wc, Ws, t);
    __syncthreads();
    compute_tile(Xs, Ws, tx, ty, acc);
    write_tile_bf16(Ws, tx, ty, acc, bc, oc16, row0, t);
}

// ---------------------------------------------------------------------------
// Stats of u = rel @ pos_w1^T + pos_b1 over E edges -> slot atomics (8/slot32).
__global__ __launch_bounds__(256)
void k_pos_stats(const float* __restrict__ pos, const int* __restrict__ src,
                 const float* __restrict__ pw1, const float* __restrict__ pb1,
                 float* __restrict__ acc)
{
    float s0 = 0, s1 = 0, s2 = 0, q0 = 0, q1 = 0, q2 = 0;
    int tid = blockIdx.x * 256 + threadIdx.x;
    for (int e = tid; e < E_; e += 1024 * 256) {
        int si = src[e], di = e >> 4;
        float rx = pos[3 * si + 0] - pos[3 * di + 0];
        float ry = pos[3 * si + 1] - pos[3 * di + 1];
        float rz = pos[3 * si + 2] - pos[3 * di + 2];
        float u0 = fmaf(rx, pw1[0], fmaf(ry, pw1[1], fmaf(rz, pw1[2], pb1[0])));
        float u1 = fmaf(rx, pw1[3], fmaf(ry, pw1[4], fmaf(rz, pw1[5], pb1[1])));
        float u2 = fmaf(rx, pw1[6], fmaf(ry, pw1[7], fmaf(rz, pw1[8], pb1[2])));
        s0 += u0; q0 = fmaf(u0, u0, q0);
        s1 += u1; q1 = fmaf(u1, u1, q1);
        s2 += u2; q2 = fmaf(u2, u2, q2);
    }
#pragma unroll
    for (int m = 1; m < 64; m <<= 1) {
        s0 += __shfl_xor(s0, m, 64); s1 += __shfl_xor(s1, m, 64); s2 += __shfl_xor(s2, m, 64);
        q0 += __shfl_xor(q0, m, 64); q1 += __shfl_xor(q1, m, 64); q2 += __shfl_xor(q2, m, 64);
    }
    __shared__ float red[4][8];
    int wv = threadIdx.x >> 6, ln = threadIdx.x & 63;
    if (ln == 0) {
        red[wv][0] = s0; red[wv][1] = s1; red[wv][2] = s2; red[wv][3] = 0.f;
        red[wv][4] = q0; red[wv][5] = q1; red[wv][6] = q2; red[wv][7] = 0.f;
    }
    __syncthreads();
    if (threadIdx.x < 8)
        atomicAdd(&acc[(blockIdx.x & (NSLOT - 1)) * 32 + threadIdx.x],
                  red[0][threadIdx.x] + red[1][threadIdx.x] + red[2][threadIdx.x] + red[3][threadIdx.x]);
}

// ---------------------------------------------------------------------------
// Stats of a = bf16(a_src)[src]-a_dst[dst]+delta. Grid 2048 x 256.
__global__ __launch_bounds__(256)
void k_abn1_stats(const float* __restrict__ pos, const int* __restrict__ src,
                  const unsigned short* __restrict__ asrc16,
                  const float* __restrict__ adst,
                  const float* __restrict__ pw1, const float* __restrict__ pb1,
                  const float* __restrict__ accpos, const float* __restrict__ pbg,
                  const float* __restrict__ pbb, const float* __restrict__ pw2,
                  const float* __restrict__ pb2, float* __restrict__ acc_a1)
{
    __shared__ float rawP[8];
    int t = threadIdx.x;
    int l = t & 15, g = t >> 4, wv = t >> 6;
    int c0 = 4 * l;
    if (t < 8) {
        float s = 0.f;
        for (int sl = 0; sl < NSLOT; ++sl) s += accpos[sl * 32 + t];
        rawP[t] = s;
    }
    __syncthreads();
    float ps0, ph0, ps1, ph1, ps2, ph2;
    bn_ss(rawP, 4, 0, INV_E, pbg, pbb, ps0, ph0);
    bn_ss(rawP, 4, 1, INV_E, pbg, pbb, ps1, ph1);
    bn_ss(rawP, 4, 2, INV_E, pbg, pbb, ps2, ph2);
    float4 p0 = *(const float4*)(pw2 + 12 * l);
    float4 p1 = *(const float4*)(pw2 + 12 * l + 4);
    float4 p2 = *(const float4*)(pw2 + 12 * l + 8);
    float4 pb = *(const float4*)(pb2 + c0);
    float sa0 = 0, sa1 = 0, sa2 = 0, sa3 = 0;
    float qa0 = 0, qa1 = 0, qa2 = 0, qa3 = 0;
#pragma unroll
    for (int nn = 0; nn < 2; ++nn) {
        int n = blockIdx.x * 32 + nn * 16 + g;
        float4 dv = *(const float4*)(adst + (size_t)n * 64 + c0);
        float pnx = pos[3 * n + 0], pny = pos[3 * n + 1], pnz = pos[3 * n + 2];
        int si_l = src[n * 16 + l];
        float rx = pos[3 * si_l + 0] - pnx;
        float ry = pos[3 * si_l + 1] - pny;
        float rz = pos[3 * si_l + 2] - pnz;
        float u0 = fmaf(rx, pw1[0], fmaf(ry, pw1[1], fmaf(rz, pw1[2], pb1[0])));
        float u1 = fmaf(rx, pw1[3], fmaf(ry, pw1[4], fmaf(rz, pw1[5], pb1[1])));
        float u2 = fmaf(rx, pw1[6], fmaf(ry, pw1[7], fmaf(rz, pw1[8], pb1[2])));
        float dl0 = fmaxf(fmaf(u0, ps0, ph0), 0.f);
        float dl1 = fmaxf(fmaf(u1, ps1, ph1), 0.f);
        float dl2 = fmaxf(fmaf(u2, ps2, ph2), 0.f);
        for (int k = 0; k < 16; ++k) {
            int si = __shfl(si_l, k, 16);
            float d0 = __shfl(dl0, k, 16);
            float d1 = __shfl(dl1, k, 16);
            float d2 = __shfl(dl2, k, 16);
            uint2 raw = ((const uint2*)asrc16)[(size_t)si * 16 + l];
            float avx = bf16_lo(raw.x), avy = bf16_hi(raw.x);
            float avz = bf16_lo(raw.y), avw = bf16_hi(raw.y);
            float del0 = fmaf(d0, p0.x, fmaf(d1, p0.y, fmaf(d2, p0.z, pb.x)));
            float del1 = fmaf(d0, p0.w, fmaf(d1, p1.x, fmaf(d2, p1.y, pb.y)));
            float del2 = fmaf(d0, p1.z, fmaf(d1, p1.w, fmaf(d2, p2.x, pb.z)));
            float del3 = fmaf(d0, p2.y, fmaf(d1, p2.z, fmaf(d2, p2.w, pb.w)));
            float a0 = avx - dv.x + del0;
            float a1 = avy - dv.y + del1;
            float a2 = avz - dv.z + del2;
            float a3 = avw - dv.w + del3;
            sa0 += a0; qa0 = fmaf(a0, a0, qa0);
            sa1 += a1; qa1 = fmaf(a1, a1, qa1);
            sa2 += a2; qa2 = fmaf(a2, a2, qa2);
            sa3 += a3; qa3 = fmaf(a3, a3, qa3);
        }
    }
#pragma unroll
    for (int m = 16; m <= 32; m <<= 1) {
        sa0 += __shfl_xor(sa0, m, 64); sa1 += __shfl_xor(sa1, m, 64);
        sa2 += __shfl_xor(sa2, m, 64); sa3 += __shfl_xor(sa3, m, 64);
        qa0 += __shfl_xor(qa0, m, 64); qa1 += __shfl_xor(qa1, m, 64);
        qa2 += __shfl_xor(qa2, m, 64); qa3 += __shfl_xor(qa3, m, 64);
    }
    __shared__ float red[4][128];
    if ((t & 63) < 16) {
        red[wv][c0 + 0] = sa0; red[wv][c0 + 1] = sa1;
        red[wv][c0 + 2] = sa2; red[wv][c0 + 3] = sa3;
        red[wv][64 + c0 + 0] = qa0; red[wv][64 + c0 + 1] = qa1;
        red[wv][64 + c0 + 2] = qa2; red[wv][64 + c0 + 3] = qa3;
    }
    __syncthreads();
    if (t < 128)
        atomicAdd(&acc_a1[(blockIdx.x & (NSLOT - 1)) * 128 + t],
                  red[0][t] + red[1][t] + red[2][t] + red[3][t]);
}

// ---------------------------------------------------------------------------
// t1 = relu(abn1(a)) @ attn_w1^T + attn_b1; abn2 stats -> slot atomics.
__global__ __launch_bounds__(256)
void k_edge_t1(const float* __restrict__ pos, const int* __restrict__ src,
               const unsigned short* __restrict__ asrc16,
               const float* __restrict__ adst,
               const float* __restrict__ pw1, const float* __restrict__ pb1,
               const float* __restrict__ accpos, const float* __restrict__ pbg,
               const float* __restrict__ pbb, const float* __restrict__ pw2,
               const float* __restrict__ pb2, const float* __restrict__ acc_a1,
               const float* __restrict__ a1g, const float* __restrict__ a1b,
               const float* __restrict__ aw1, const float* __restrict__ ab1,
               float* __restrict__ t1, float* __restrict__ acc_a2)
{
    __shared__ float rawA1[128];
    __shared__ float rawP[8];
    int t = threadIdx.x;
    int l = t & 15, g = t >> 4, wv = t >> 6;
    int c0 = 4 * l;
    int ch = 4 * (l & 1) + 2 * ((l >> 1) & 1) + ((l >> 2) & 1);
    float abv = ab1[ch];
    if (t < 128) {
        float s = 0.f;
        for (int sl = 0; sl < NSLOT; ++sl) s += acc_a1[sl * 128 + t];
        rawA1[t] = s;
    } else if (t < 136) {
        int i = t - 128;
        float s = 0.f;
        for (int sl = 0; sl < NSLOT; ++sl) s += accpos[sl * 32 + i];
        rawP[i] = s;
    }
    __syncthreads();
    float ps0, ph0, ps1, ph1, ps2, ph2;
    bn_ss(rawP, 4, 0, INV_E, pbg, pbb, ps0, ph0);
    bn_ss(rawP, 4, 1, INV_E, pbg, pbb, ps1, ph1);
    bn_ss(rawP, 4, 2, INV_E, pbg, pbb, ps2, ph2);
    float scx, shx, scy, shy, scz, shz, scw, shw;
    bn_ss(rawA1, 64, c0 + 0, INV_E, a1g, a1b, scx, shx);
    bn_ss(rawA1, 64, c0 + 1, INV_E, a1g, a1b, scy, shy);
    bn_ss(rawA1, 64, c0 + 2, INV_E, a1g, a1b, scz, shz);
    bn_ss(rawA1, 64, c0 + 3, INV_E, a1g, a1b, scw, shw);
    float4 p0 = *(const float4*)(pw2 + 12 * l);
    float4 p1 = *(const float4*)(pw2 + 12 * l + 4);
    float4 p2 = *(const float4*)(pw2 + 12 * l + 8);
    float4 pb = *(const float4*)(pb2 + c0);
    float4 w1[8];
#pragma unroll
    for (int jj = 0; jj < 8; ++jj) w1[jj] = *(const float4*)(aw1 + jj * 64 + c0);
    float sse = 0.f, ssq = 0.f;
#pragma unroll
    for (int nn = 0; nn < 2; ++nn) {
        int n = blockIdx.x * 32 + nn * 16 + g;
        float4 dv = *(const float4*)(adst + (size_t)n * 64 + c0);
        float pnx = pos[3 * n + 0], pny = pos[3 * n + 1], pnz = pos[3 * n + 2];
        int si_l = src[n * 16 + l];
        float rx = pos[3 * si_l + 0] - pnx;
        float ry = pos[3 * si_l + 1] - pny;
        float rz = pos[3 * si_l + 2] - pnz;
        float u0 = fmaf(rx, pw1[0], fmaf(ry, pw1[1], fmaf(rz, pw1[2], pb1[0])));
        float u1 = fmaf(rx, pw1[3], fmaf(ry, pw1[4], fmaf(rz, pw1[5], pb1[1])));
        float u2 = fmaf(rx, pw1[6], fmaf(ry, pw1[7], fmaf(rz, pw1[8], pb1[2])));
        float dl0 = fmaxf(fmaf(u0, ps0, ph0), 0.f);
        float dl1 = fmaxf(fmaf(u1, ps1, ph1), 0.f);
        float dl2 = fmaxf(fmaf(u2, ps2, ph2), 0.f);
        for (int k = 0; k < 16; ++k) {
            int si = __shfl(si_l, k, 16);
            float d0 = __shfl(dl0, k, 16);
            float d1 = __shfl(dl1, k, 16);
            float d2 = __shfl(dl2, k, 16);
            uint2 raw = ((const uint2*)asrc16)[(size_t)si * 16 + l];
            float avx = bf16_lo(raw.x), avy = bf16_hi(raw.x);
            float avz = bf16_lo(raw.y), avw = bf16_hi(raw.y);
            float del0 = fmaf(d0, p0.x, fmaf(d1, p0.y, fmaf(d2, p0.z, pb.x)));
            float del1 = fmaf(d0, p0.w, fmaf(d1, p1.x, fmaf(d2, p1.y, pb.y)));
            float del2 = fmaf(d0, p1.z, fmaf(d1, p1.w, fmaf(d2, p2.x, pb.z)));
            float del3 = fmaf(d0, p2.y, fmaf(d1, p2.z, fmaf(d2, p2.w, pb.w)));
            float an0 = fmaxf(fmaf(avx - dv.x + del0, scx, shx), 0.f);
            float an1 = fmaxf(fmaf(avy - dv.y + del1, scy, shy), 0.f);
            float an2 = fmaxf(fmaf(avz - dv.z + del2, scz, shz), 0.f);
            float an3 = fmaxf(fmaf(avw - dv.w + del3, scw, shw), 0.f);
            float tp[8];
#pragma unroll
            for (int jj = 0; jj < 8; ++jj)
                tp[jj] = fmaf(an0, w1[jj].x, fmaf(an1, w1[jj].y,
                         fmaf(an2, w1[jj].z, an3 * w1[jj].w)));
            // reduce-scatter: 8 -> 4 -> 2 -> 1 values
            float s4[4];
#pragma unroll
            for (int j = 0; j < 4; ++j) {
                float send = (l & 1) ? tp[j] : tp[j + 4];
                float recv = __shfl_xor(send, 1, 64);
                s4[j] = ((l & 1) ? tp[j + 4] : tp[j]) + recv;
            }
            float s2[2];
#pragma unroll
            for (int j = 0; j < 2; ++j) {
                float send = (l & 2) ? s4[j] : s4[j + 2];
                float recv = __shfl_xor(send, 2, 64);
                s2[j] = ((l & 2) ? s4[j + 2] : s4[j]) + recv;
            }
            float send = (l & 4) ? s2[0] : s2[1];
            float recv = __shfl_xor(send, 4, 64);
            float s1 = ((l & 4) ? s2[1] : s2[0]) + recv;
            s1 += __shfl_xor(s1, 8, 64);
            float o = s1 + abv;
            if (l < 8) t1[(size_t)(n * 16 + k) * 8 + ch] = o;
            sse += o; ssq = fmaf(o, o, ssq);
        }
    }
#pragma unroll
    for (int m = 16; m <= 32; m <<= 1) {
        sse += __shfl_xor(sse, m, 64);
        ssq += __shfl_xor(ssq, m, 64);
    }
    __shared__ float red[4][16];
    if ((t & 63) < 8) { red[wv][ch] = sse; red[wv][8 + ch] = ssq; }
    __syncthreads();
    if (t < 16)
        atomicAdd(&acc_a2[(blockIdx.x & (NSLOT - 1)) * 32 + t],
                  red[0][t] + red[1][t] + red[2][t] + red[3][t]);
}

// ---------------------------------------------------------------------------
// Softmax + weighted aggregate, group-per-node; bn2 stats -> slot atomics.
// Grid 4096 x 256 (16 nodes/blk).
__global__ __launch_bounds__(256)
void k_node_aggr(const float* __restrict__ pos, const int* __restrict__ src,
                 const float* __restrict__ t1, const float* __restrict__ acc_a2,
                 const float* __restrict__ a2g, const float* __restrict__ a2b,
                 const float* __restrict__ aw2, const float* __restrict__ ab2,
                 const unsigned short* __restrict__ hw16,
                 const float* __restrict__ accpos, const float* __restrict__ pbg,
                 const float* __restrict__ pbb,
                 const float* __restrict__ pw1, const float* __restrict__ pb1,
                 const float* __restrict__ pw2, const float* __restrict__ pb2,
                 float* __restrict__ out, float* __restrict__ acc_bn2)
{
    __shared__ float alds[16][196];   // [group][k*12 + ch8]; later stats scratch
    __shared__ float ssm2[16];
    __shared__ float rawA2[16];
    __shared__ float rawP[8];
    int t = threadIdx.x, l = t & 15, g = t >> 4;
    int c0 = 4 * l;
    if (t < 16) {
        float s = 0.f;
        for (int sl = 0; sl < NSLOT; ++sl) s += acc_a2[sl * 32 + t];
        rawA2[t] = s;
    } else if (t < 24) {
        int i = t - 16;
        float s = 0.f;
        for (int sl = 0; sl < NSLOT; ++sl) s += accpos[sl * 32 + i];
        rawP[i] = s;
    }
    __syncthreads();
    if (t < 8) {
        float scv, shv;
        bn_ss(rawA2, 8, t, INV_E, a2g, a2b, scv, shv);
        ssm2[t] = scv; ssm2[8 + t] = shv;
    }
    __syncthreads();
    float ps0, ph0, ps1, ph1, ps2, ph2;
    bn_ss(rawP, 4, 0, INV_E, pbg, pbb, ps0, ph0);
    bn_ss(rawP, 4, 1, INV_E, pbg, pbb, ps1, ph1);
    bn_ss(rawP, 4, 2, INV_E, pbg, pbb, ps2, ph2);
    float4 p0 = *(const float4*)(pw2 + 12 * l);
    float4 p1 = *(const float4*)(pw2 + 12 * l + 4);
    float4 p2 = *(const float4*)(pw2 + 12 * l + 8);
    float4 pb = *(const float4*)(pb2 + c0);
    int alof = (l & 1) * 4;
    int n = blockIdx.x * 16 + g;
    int e = n * 16 + l;
    // ---- phase A: per-edge attention logits + softmax over the group
    const float4* t4 = (const float4*)(t1 + (size_t)e * 8);
    float4 ta = t4[0], tb = t4[1];
    float tv[8] = {ta.x, ta.y, ta.z, ta.w, tb.x, tb.y, tb.z, tb.w};
    float tn[8];
#pragma unroll
    for (int j = 0; j < 8; ++j)
        tn[j] = fmaxf(fmaf(tv[j], ssm2[j], ssm2[8 + j]), 0.f);
    float al[8];
#pragma unroll
    for (int j = 0; j < 8; ++j) {
        float acc = ab2[j];
#pragma unroll
        for (int i = 0; i < 8; ++i) acc = fmaf(tn[i], aw2[j * 8 + i], acc);
        float m = acc;
#pragma unroll
        for (int msk = 1; msk < 16; msk <<= 1) m = fmaxf(m, __shfl_xor(m, msk, 64));
        float ex = __expf(acc - m);
        float sm = ex;
#pragma unroll
        for (int msk = 1; msk < 16; msk <<= 1) sm += __shfl_xor(sm, msk, 64);
        al[j] = ex / sm;
    }
    *(float4*)&alds[g][l * 12]     = make_float4(al[0], al[1], al[2], al[3]);
    *(float4*)&alds[g][l * 12 + 4] = make_float4(al[4], al[5], al[6], al[7]);
    int silane = src[e];
    float pnx = pos[3 * n + 0], pny = pos[3 * n + 1], pnz = pos[3 * n + 2];
    // own-edge d
    float rx = pos[3 * silane + 0] - pnx;
    float ry = pos[3 * silane + 1] - pny;
    float rz = pos[3 * silane + 2] - pnz;
    float u0 = fmaf(rx, pw1[0], fmaf(ry, pw1[1], fmaf(rz, pw1[2], pb1[0])));
    float u1 = fmaf(rx, pw1[3], fmaf(ry, pw1[4], fmaf(rz, pw1[5], pb1[1])));
    float u2 = fmaf(rx, pw1[6], fmaf(ry, pw1[7], fmaf(rz, pw1[8], pb1[2])));
    float dl0 = fmaxf(fmaf(u0, ps0, ph0), 0.f);
    float dl1 = fmaxf(fmaf(u1, ps1, ph1), 0.f);
    float dl2 = fmaxf(fmaf(u2, ps2, ph2), 0.f);
    // ---- phase B: accumulate own 4 channels over the node's 16 edges
    float a0 = 0.f, a1 = 0.f, a2 = 0.f, a3 = 0.f;
#pragma unroll 4
    for (int k = 0; k < 16; ++k) {
        int sk = __shfl(silane, k, 16);
        float d0 = __shfl(dl0, k, 16);
        float d1 = __shfl(dl1, k, 16);
        float d2 = __shfl(dl2, k, 16);
        uint2 raw = ((const uint2*)hw16)[(size_t)sk * 16 + l];
        float hvx = bf16_lo(raw.x), hvy = bf16_hi(raw.x);
        float hvz = bf16_lo(raw.y), hvw = bf16_hi(raw.y);
        float4 alv = *(const float4*)&alds[g][k * 12 + alof];
        float del0 = fmaf(d0, p0.x, fmaf(d1, p0.y, fmaf(d2, p0.z, pb.x)));
        float del1 = fmaf(d0, p0.w, fmaf(d1, p1.x, fmaf(d2, p1.y, pb.y)));
        float del2 = fmaf(d0, p1.z, fmaf(d1, p1.w, fmaf(d2, p2.x, pb.z)));
        float del3 = fmaf(d0, p2.y, fmaf(d1, p2.z, fmaf(d2, p2.w, pb.w)));
        a0 = fmaf(alv.x, hvx + del0, a0);
        a1 = fmaf(alv.y, hvy + del1, a1);
        a2 = fmaf(alv.z, hvz + del2, a2);
        a3 = fmaf(alv.w, hvw + del3, a3);
    }
    *(float4*)(out + (size_t)n * 64 + c0) = make_float4(a0, a1, a2, a3);
    // ---- bn2 stats: reduce over the block's 16 nodes per channel
    __syncthreads();   // all alds reads done
    float4* scr = (float4*)&alds[0][0];   // 512 float4 <= 3136 floats OK
    scr[g * 16 + l]       = make_float4(a0, a1, a2, a3);
    scr[256 + g * 16 + l] = make_float4(a0 * a0, a1 * a1, a2 * a2, a3 * a3);
    __syncthreads();
    if (t < 16) {   // thread t handles channels 4t..4t+3
        float4 S = make_float4(0, 0, 0, 0), Q = make_float4(0, 0, 0, 0);
#pragma unroll
        for (int k = 0; k < 16; ++k) {
            float4 a = scr[k * 16 + t], b = scr[256 + k * 16 + t];
            S.x += a.x; S.y += a.y; S.z += a.z; S.w += a.w;
            Q.x += b.x; Q.y += b.y; Q.z += b.z; Q.w += b.w;
        }
        float* ao = acc_bn2 + (blockIdx.x & (NSLOT - 1)) * 128;
        atomicAdd(&ao[4 * t + 0], S.x); atomicAdd(&ao[4 * t + 1], S.y);
        atomicAdd(&ao[4 * t + 2], S.z); atomicAdd(&ao[4 * t + 3], S.w);
        atomicAdd(&ao[64 + 4 * t + 0], Q.x); atomicAdd(&ao[64 + 4 * t + 1], Q.y);
        atomicAdd(&ao[64 + 4 * t + 2], Q.z); atomicAdd(&ao[64 + 4 * t + 3], Q.w);
    }
}

// ---------------------------------------------------------------------------
// out = relu(bn3(y3) + x_skip); bn3 from slots.
__global__ __launch_bounds__(256)
void k_final(const float* __restrict__ y3, const float* __restrict__ acc3,
             const float* __restrict__ g3, const float* __restrict__ b3,
             const float* __restrict__ x, float* __restrict__ out)
{
    __shared__ float raws[128];
    __shared__ float ssl[128];
    int t = threadIdx.x;
    if (t < 128) {
        float s = 0.f;
        for (int sl = 0; sl < NSLOT; ++sl) s += acc3[sl * 128 + t];
        raws[t] = s;
    }
    __syncthreads();
    if (t < 64) {
        float scv, shv;
        bn_ss(raws, 64, t, INV_N, g3, b3, scv, shv);
        ssl[t] = scv; ssl[64 + t] = shv;
    }
    __syncthreads();
    int i = blockIdx.x * 256 + t;   // float4 index
    int c4 = i & 15;
    float4 sc = *(const float4*)&ssl[4 * c4];
    float4 sh = *(const float4*)&ssl[64 + 4 * c4];
    float4 v  = ((const float4*)y3)[i];
    float4 xs = ((const float4*)x)[i];
    float4 o;
    o.x = fmaxf(fmaf(v.x, sc.x, sh.x) + xs.x, 0.f);
    o.y = fmaxf(fmaf(v.y, sc.y, sh.y) + xs.y, 0.f);
    o.z = fmaxf(fmaf(v.z, sc.z, sh.z) + xs.z, 0.f);
    o.w = fmaxf(fmaf(v.w, sc.w, sh.w) + xs.w, 0.f);
    ((float4*)out)[i] = o;
}

// ---------------------------------------------------------------------------
extern "C" void kernel_launch(void* const* d_in, const int* in_sizes, int n_in,
                              void* d_out, int out_size, void* d_ws, size_t ws_size,
                              hipStream_t stream)
{
    const float* x    = (const float*)d_in[0];
    const float* pos  = (const float*)d_in[1];
    const int*   src  = (const int*)d_in[2];           // edge_index row 0
    const float* W_in = (const float*)d_in[3];
    const float* W_out= (const float*)d_in[4];
    const float* pw1  = (const float*)d_in[5];
    const float* pb1  = (const float*)d_in[6];
    const float* pbg  = (const float*)d_in[7];
    const float* pbb  = (const float*)d_in[8];
    const float* pw2  = (const float*)d_in[9];
    const float* pb2  = (const float*)d_in[10];
    const float* a1g  = (const float*)d_in[11];
    const float* a1b  = (const float*)d_in[12];
    const float* aw1  = (const float*)d_in[13];
    const float* ab1  = (const float*)d_in[14];
    const float* a2g  = (const float*)d_in[15];
    const float* a2b  = (const float*)d_in[16];
    const float* aw2  = (const float*)d_in[17];
    const float* ab2  = (const float*)d_in[18];
    const float* linw = (const float*)d_in[19];
    const float* linb = (const float*)d_in[20];
    const float* srcw = (const float*)d_in[21];
    const float* srcb = (const float*)d_in[22];
    const float* dstw = (const float*)d_in[23];
    const float* dstb = (const float*)d_in[24];
    const float* bn1g = (const float*)d_in[25];
    const float* bn1b = (const float*)d_in[26];
    const float* bn2g = (const float*)d_in[27];
    const float* bn2b = (const float*)d_in[28];
    const float* bn3g = (const float*)d_in[29];
    const float* bn3b = (const float*)d_in[30];
    float* outp = (float*)d_out;

    float* ws = (float*)d_ws;
    const size_t NC = (size_t)N_ * C_;
    float* buf_y     = ws;                       // y1, later y3
    float* buf_adst  = ws + NC;                  // a_dst f32; later reused as out
    unsigned short* asrc16 = (unsigned short*)(ws + 2 * NC);       // NC/2 floats
    unsigned short* hw16   = (unsigned short*)(ws + 2 * NC + NC / 2);
    float* buf_t1    = ws + 3 * NC;              // [E,8] f32
    float* accb      = ws + 3 * NC + (size_t)E_ * 8;
    // 64 slots each, line-aligned strides:
    float* acc_bn1 = accb;                    // 64 x 128
    float* acc_pos = accb + 64 * 128;         // 64 x 32
    float* acc_a1  = acc_pos + 64 * 32;       // 64 x 128
    float* acc_a2  = acc_a1 + 64 * 128;       // 64 x 32
    float* acc_bn2 = acc_a2 + 64 * 32;        // 64 x 128
    float* acc_bn3 = acc_bn2 + 64 * 128;      // 64 x 128   (total 36864 floats)
    const int ACC_TOTAL = 64 * (128 + 32 + 128 + 32 + 128 + 128);
    // buf_out aliases buf_adst: adst last read by k_edge_t1.
    float* buf_out = buf_adst;

    // 0) zero BN slot accumulators
    k_zero<<<(ACC_TOTAL + 1023) / 1024, 1024, 0, stream>>>(accb, ACC_TOTAL);
    // 1) y1 = x @ W_in^T (+ slot bn1 stats)
    k_gemm_tile<<<1024, 256, 0, stream>>>(x, W_in, nullptr, nullptr, nullptr, 0.f,
                                          buf_y, acc_bn1);
    // 2) h = relu(bn1(y1)); asrc16 (bf16) / adst (f32) / hw16 (bf16)
    k_gemm3_tile<<<1024, 256, 0, stream>>>(buf_y, acc_bn1, bn1g, bn1b,
                                           srcw, srcb, dstw, dstb, linw, linb,
                                           asrc16, buf_adst, hw16);
    // 3) pos-BN stats (slot atomics)
    k_pos_stats<<<1024, 256, 0, stream>>>(pos, src, pw1, pb1, acc_pos);
    // 4) attn_bn1 stats (slot atomics)
    k_abn1_stats<<<2048, 256, 0, stream>>>(pos, src, asrc16, buf_adst,
                                           pw1, pb1, acc_pos, pbg, pbb,
                                           pw2, pb2, acc_a1);
    // 5) t1 + abn2 stats (slot atomics)
    k_edge_t1<<<2048, 256, 0, stream>>>(pos, src, asrc16, buf_adst,
                                        pw1, pb1, acc_pos, pbg, pbb, pw2, pb2,
                                        acc_a1, a1g, a1b, aw1, ab1,
                                        buf_t1, acc_a2);
    // 6) softmax + weighted aggregate -> out (+ slot bn2 stats)
    k_node_aggr<<<4096, 256, 0, stream>>>(pos, src, buf_t1, acc_a2, a2g, a2b,
                                          aw2, ab2, hw16, acc_pos, pbg, pbb,
                                          pw1, pb1, pw2, pb2, buf_out, acc_bn2);
    // 7) y3 = relu(bn2(out)) @ W_out^T (+ slot bn3 stats)
    k_gemm_tile<<<1024, 256, 0, stream>>>(buf_out, W_out, acc_bn2, bn2g, bn2b, INV_N,
                                          buf_y, acc_bn3);
    // 8) out = relu(bn3(y3) + x)
    k_final<<<(N_ * C_ / 4) / 256, 256, 0, stream>>>(buf_y, acc_bn3, bn3g, bn3b, x, outp);

    (void)in_sizes; (void)n_in; (void)out_size; (void)ws_size;
}